// Round 10
// baseline (445.623 us; speedup 1.0000x reference)
//
#include <hip/hip_runtime.h>
#include <hip/hip_bf16.h>
#include <stdint.h>

typedef short short8 __attribute__((ext_vector_type(8)));
typedef float f32x4  __attribute__((ext_vector_type(4)));

static constexpr int O_TOT = 28672;
static constexpr int K_TOT = 8192;
static constexpr int M_ROWS = 8;
static constexpr int KW = 1024;            // packed int32 words per output row

// workspace layout
static constexpr size_t WS_X    = 4096;                           // 8 x 8192 bf16 = 128KB
static constexpr size_t WS_SG   = WS_X + (size_t)8 * K_TOT * 2;   // 64x8 f32 = 2KB
static constexpr size_t WS_PART = WS_SG + 64 * 8 * 4;             // 448 slabs x 16KB = 7.34MB
static constexpr size_t PART_BYTES = (size_t)448 * 8 * 8 * 64 * 4;
static constexpr size_t WS_CTR  = WS_PART + PART_BYTES;           // 448 ints
static constexpr size_t WS_NEED_V10 = WS_CTR + 448 * 4 + 64;
static constexpr size_t WS_NEED_R7  = WS_PART + 64;

// mode: 0 = bf16, 1 = fp16, 2 = f32
__device__ __forceinline__ float dec16(uint16_t u, int mode) {
  if (mode == 0) {
    union { uint32_t i; float f; } v; v.i = ((uint32_t)u) << 16; return v.f;
  } else {
    union { uint16_t u; _Float16 h; } v; v.u = u; return (float)v.h;
  }
}
__device__ __forceinline__ uint16_t f2bf_bits(float f) {
  union { __hip_bfloat16 b; uint16_t u; } v; v.b = __float2bfloat16(f); return v.u;
}
__device__ __forceinline__ uint16_t f2h_bits(float f) {
  union { uint16_t u; _Float16 h; } v; v.h = (_Float16)f; return v.u;
}

// --- standalone sniffer (only for tiny-ws bottom tier) ---
__global__ void sniff_kernel(const uint16_t* __restrict__ x, int* __restrict__ flag) {
  const int t = threadIdx.x;
  int ce = 0, co = 0;
  #pragma unroll
  for (int i = 0; i < 2; ++i) {
    const uint4 u = *reinterpret_cast<const uint4*>(x + (size_t)(t + 64 * i) * 8);
    const uint32_t d[4] = {u.x, u.y, u.z, u.w};
    #pragma unroll
    for (int j = 0; j < 4; ++j) {
      const int elo = (d[j] >> 7)  & 0xFF;
      const int ehi = (d[j] >> 23) & 0xFF;
      ce += (elo >= 118 && elo <= 131);
      co += (ehi >= 118 && ehi <= 131);
    }
  }
  for (int d = 32; d; d >>= 1) { ce += __shfl_xor(ce, d); co += __shfl_xor(co, d); }
  if (t == 0) {
    int mode;
    if (ce > 358 && co > 358)      mode = 0;
    else if (co > 358)             mode = 2;
    else                           mode = 1;
    *flag = mode;
  }
}

// --- prep_all: self-sniff + flag + ctr-zero + x decode/permute + group sums ---
__global__ __launch_bounds__(256)
void prep_all_kernel(const uint16_t* __restrict__ x16, uint8_t* __restrict__ ws,
                     int* __restrict__ ctr, int do_ctr) {
  __shared__ int msh[4];
  __shared__ float psum[256];
  const int t = threadIdx.x;
  const int wv = t >> 6, lane = t & 63;

  // self-sniff: all blocks classify the SAME first 1024 elements of x (L2-hot)
  int mode;
  {
    const uint4 u = reinterpret_cast<const uint4*>(x16)[t];
    const uint32_t d[4] = {u.x, u.y, u.z, u.w};
    int ce = 0, co = 0;
    #pragma unroll
    for (int j = 0; j < 4; ++j) {
      const int elo = (d[j] >> 7)  & 0xFF;
      const int ehi = (d[j] >> 23) & 0xFF;
      ce += (elo >= 118 && elo <= 131);
      co += (ehi >= 118 && ehi <= 131);
    }
    for (int s = 32; s; s >>= 1) { ce += __shfl_xor(ce, s); co += __shfl_xor(co, s); }
    if (lane == 0) msh[wv] = (ce << 16) | co;
    __syncthreads();
    int CE = 0, CO = 0;
    #pragma unroll
    for (int w = 0; w < 4; ++w) { CE += msh[w] >> 16; CO += msh[w] & 0xffff; }
    mode = (CE > 716 && CO > 716) ? 0 : ((CO > 716) ? 2 : 1);
  }
  if (blockIdx.x == 0) {
    if (t == 0) *reinterpret_cast<int*>(ws) = mode;
    if (do_ctr && t < 112) reinterpret_cast<uint4*>(ctr)[t] = make_uint4(0, 0, 0, 0);
  }

  // x decode -> bf16, permuted 0,4,1,5,2,6,3,7 per 8-block (verified R5-R9)
  const int tid = blockIdx.x * 256 + t;             // 32 blocks x 256 = 8192
  const int r = tid >> 10, wb = tid & 1023;
  uint16_t s[8];
  if (mode == 2) {
    const float* xF = (const float*)x16;
    #pragma unroll
    for (int j = 0; j < 8; ++j) s[j] = f2bf_bits(xF[(size_t)r * K_TOT + wb * 8 + j]);
  } else {
    const uint4 u = *reinterpret_cast<const uint4*>(x16 + (size_t)r * K_TOT + wb * 8);
    const uint32_t d[4] = {u.x, u.y, u.z, u.w};
    #pragma unroll
    for (int j = 0; j < 8; ++j) {
      const uint16_t raw = (j & 1) ? (uint16_t)(d[j >> 1] >> 16) : (uint16_t)(d[j >> 1] & 0xffffu);
      s[j] = (mode == 0) ? raw : f2bf_bits(dec16(raw, 1));
    }
  }
  uint16_t p[8];
  p[0] = s[0]; p[1] = s[4]; p[2] = s[1]; p[3] = s[5];
  p[4] = s[2]; p[5] = s[6]; p[6] = s[3]; p[7] = s[7];
  uint4 o;
  o.x = (uint32_t)p[0] | ((uint32_t)p[1] << 16);
  o.y = (uint32_t)p[2] | ((uint32_t)p[3] << 16);
  o.z = (uint32_t)p[4] | ((uint32_t)p[5] << 16);
  o.w = (uint32_t)p[6] | ((uint32_t)p[7] << 16);
  *reinterpret_cast<uint4*>((uint16_t*)(ws + WS_X) + (size_t)r * K_TOT + wb * 8) = o;

  float loc = 0.f;
  #pragma unroll
  for (int j = 0; j < 8; ++j) loc += dec16(p[j], 0);
  psum[t] = loc;
  __syncthreads();
  #pragma unroll
  for (int st = 8; st; st >>= 1) {
    if ((t & 15) < st) psum[t] += psum[t + st];
    __syncthreads();
  }
  if ((t & 15) == 0) {
    const int g = t >> 4;
    const int G = (blockIdx.x & 3) * 16 + g;
    ((float*)(ws + WS_SG))[G * 8 + r] = psum[t];
  }
}

// --- v10 main: v9 body + issue-early q loads + fused split-K reduce ---
__global__ __launch_bounds__(256)
void wq_mfma4_kernel(const uint32_t* __restrict__ qweight,
                     const uint32_t* __restrict__ qzeros,
                     const uint16_t* __restrict__ sc16,
                     const uint16_t* __restrict__ b16,
                     void* __restrict__ outv,
                     const uint8_t* __restrict__ ws,
                     float* __restrict__ part,
                     int* __restrict__ ctr,
                     const int* __restrict__ flag)
{
  __shared__ __align__(16) uint4 xl[8 * 129];   // 16.5KB
  __shared__ float sgl[64];
  __shared__ int lastsh;
  const int mode = *flag;
  const int t = threadIdx.x, wid = t >> 6, lane = t & 63;
  const int c = lane & 15, g4 = lane >> 4;
  const int bi = blockIdx.x;
  const int ct = bi >> 3, kq = bi & 7;
  const int cg = ct * 64 + wid * 16 + c;

  // issue ALL 8 qweight loads FIRST: latency hides under x staging + barrier
  const uint32_t* qp = qweight + (size_t)cg * KW + kq * 128;
  uint4 q[8];
  #pragma unroll
  for (int T = 0; T < 8; ++T)
    q[T] = *reinterpret_cast<const uint4*>(qp + 16 * T + 4 * g4);

  const uint32_t qzw = qzeros[cg * 8 + kq];
  float sv[8];
  if (mode == 2) {
    const float* sp = (const float*)sc16 + (size_t)cg * 64 + kq * 8;
    const f32x4 s0 = *reinterpret_cast<const f32x4*>(sp);
    const f32x4 s1 = *reinterpret_cast<const f32x4*>(sp + 4);
    sv[0] = s0[0]; sv[1] = s0[1]; sv[2] = s0[2]; sv[3] = s0[3];
    sv[4] = s1[0]; sv[5] = s1[1]; sv[6] = s1[2]; sv[7] = s1[3];
  } else {
    const uint4 sr = *reinterpret_cast<const uint4*>(sc16 + (size_t)cg * 64 + kq * 8);
    const uint32_t sd[4] = {sr.x, sr.y, sr.z, sr.w};
    #pragma unroll
    for (int j = 0; j < 4; ++j) {
      sv[2*j]   = dec16((uint16_t)(sd[j] & 0xffffu), mode);
      sv[2*j+1] = dec16((uint16_t)(sd[j] >> 16), mode);
    }
  }

  // stage x chunk (1024 uint4) + group sums
  {
    const uint4* src = (const uint4*)(ws + WS_X);
    #pragma unroll
    for (int j = 0; j < 4; ++j) {
      const int idx = j * 256 + t;
      const int r = idx >> 7, w = idx & 127;
      xl[r * 129 + w] = src[(size_t)r * 1024 + kq * 128 + w];
    }
    if (t < 64) sgl[t] = ((const float*)(ws + WS_SG))[kq * 64 + t];
  }
  __syncthreads();

  f32x4 D = {0.f, 0.f, 0.f, 0.f};
  #pragma unroll
  for (int T = 0; T < 8; ++T) {
    const uint4 a0 = xl[(c & 7) * 129 + 16 * T + 4 * g4 + 0];
    const uint4 a1 = xl[(c & 7) * 129 + 16 * T + 4 * g4 + 1];
    const uint4 a2 = xl[(c & 7) * 129 + 16 * T + 4 * g4 + 2];
    const uint4 a3 = xl[(c & 7) * 129 + 16 * T + 4 * g4 + 3];
    const f32x4 sgv = *reinterpret_cast<const f32x4*>(&sgl[T * 8 + (g4 & 1) * 4]);

    f32x4 tmp = {0.f, 0.f, 0.f, 0.f};
    const uint32_t wvv[4] = {q[T].x, q[T].y, q[T].z, q[T].w};
    const uint4   av[4] = {a0, a1, a2, a3};
    #pragma unroll
    for (int u = 0; u < 4; ++u) {
      union { uint32_t d[4]; short8 s; } bb;
      bb.d[0] = ( wvv[u]        & 0x000F000Fu) | 0x43004300u;
      bb.d[1] = ((wvv[u] >> 4)  & 0x000F000Fu) | 0x43004300u;
      bb.d[2] = ((wvv[u] >> 8)  & 0x000F000Fu) | 0x43004300u;
      bb.d[3] = ((wvv[u] >> 12) & 0x000F000Fu) | 0x43004300u;
      union { uint4 q; short8 s; } aa; aa.q = av[u];
      tmp = __builtin_amdgcn_mfma_f32_16x16x32_bf16(aa.s, bb.s, tmp, 0, 0, 0);
    }
    const float zf = (float)((qzw >> (T * 4)) & 15u);
    const float c128z = 128.0f + zf;
    D[0] += sv[T] * (tmp[0] - c128z * sgv[0]);
    D[1] += sv[T] * (tmp[1] - c128z * sgv[1]);
    D[2] += sv[T] * (tmp[2] - c128z * sgv[2]);
    D[3] += sv[T] * (tmp[3] - c128z * sgv[3]);
  }

  // compact partial slab: part[ct][kq][r][oo]
  if (g4 < 2) {
    float* slab = part + (size_t)ct * 4096 + (size_t)kq * 512;
    #pragma unroll
    for (int reg = 0; reg < 4; ++reg)
      slab[(g4 * 4 + reg) * 64 + wid * 16 + c] = D[reg];   // D row = (lane>>4)*4+reg (m89)
  }

  // fused split-K reduce: last-arriving block of this ct reduces its slab
  __syncthreads();
  if (t == 0) {
    __threadfence();                                  // publish partials (device scope)
    lastsh = (atomicAdd(&ctr[ct], 1) == 7);
  }
  __syncthreads();
  if (lastsh) {
    __threadfence();                                  // acquire others' partials
    const float* rs = part + (size_t)ct * 4096;
    #pragma unroll
    for (int rr = 0; rr < 2; ++rr) {
      const int idx = rr * 256 + t;
      const int r = idx >> 6, oo = idx & 63;
      float v = 0.f;
      #pragma unroll
      for (int kk = 0; kk < 8; ++kk) v += rs[(kk * 8 + r) * 64 + oo];
      const int o = ct * 64 + oo;
      v += (mode == 2) ? ((const float*)b16)[o] : dec16(b16[o], mode);
      const size_t oidx = (size_t)r * O_TOT + o;
      if (mode == 0)      ((__hip_bfloat16*)outv)[oidx] = __float2bfloat16(v);
      else if (mode == 1) ((uint16_t*)outv)[oidx] = f2h_bits(v);
      else                ((float*)outv)[oidx] = v;
    }
  }
}

// --- R7 main (verified) as mid-tier fallback ---
__global__ __launch_bounds__(256)
void wq_mfma_kernel(const uint32_t* __restrict__ qweight,
                    const uint32_t* __restrict__ qzeros,
                    const uint16_t* __restrict__ sc16,
                    const uint16_t* __restrict__ b16,
                    void* __restrict__ outv,
                    const uint8_t* __restrict__ ws,
                    const int* __restrict__ flag)
{
  __shared__ float red[4][64][4];
  const int mode = *flag;
  const float* scF = (const float*)sc16;
  const float* bF  = (const float*)b16;
  const int t = threadIdx.x, wid = t >> 6, lane = t & 63;
  const int c = lane & 15, g4 = lane >> 4;
  const int cg = blockIdx.x * 16 + c;

  const uint16_t* xb  = (const uint16_t*)(ws + WS_X);
  const float*    sgp = (const float*)(ws + WS_SG);
  const uint32_t* qp  = qweight + (size_t)cg * KW;
  const uint4*  abase = (const uint4*)(xb + (size_t)(c & 7) * K_TOT);
  const int G0   = wid * 16;
  const int boff = 4 * g4;
  const uint2 qz = *reinterpret_cast<const uint2*>(qzeros + cg * 8 + wid * 2);

  f32x4 D = {0.f, 0.f, 0.f, 0.f};
  uint4 q0 = *reinterpret_cast<const uint4*>(qp + 16 * G0 + boff);
  uint4 a0[4], a1[4]; uint4 q1;
  #pragma unroll
  for (int u = 0; u < 4; ++u) a0[u] = abase[16 * G0 + boff + u];

#define GBODY(TT, QC, AC, QN, AN)                                              \
  do {                                                                         \
    const int Gc = G0 + (TT);                                                  \
    const int Gn = (Gc + 1 <= 63) ? Gc + 1 : 63;                               \
    QN = *reinterpret_cast<const uint4*>(qp + 16 * Gn + boff);                 \
    AN[0] = abase[16 * Gn + boff + 0];                                         \
    AN[1] = abase[16 * Gn + boff + 1];                                         \
    AN[2] = abase[16 * Gn + boff + 2];                                         \
    AN[3] = abase[16 * Gn + boff + 3];                                         \
    f32x4 tmp = {0.f, 0.f, 0.f, 0.f};                                          \
    const uint32_t wvv[4] = {QC.x, QC.y, QC.z, QC.w};                          \
    _Pragma("unroll")                                                          \
    for (int u = 0; u < 4; ++u) {                                              \
      union { uint32_t d[4]; short8 s; } bb;                                   \
      bb.d[0] = ( wvv[u]        & 0x000F000Fu) | 0x43004300u;                  \
      bb.d[1] = ((wvv[u] >> 4)  & 0x000F000Fu) | 0x43004300u;                  \
      bb.d[2] = ((wvv[u] >> 8)  & 0x000F000Fu) | 0x43004300u;                  \
      bb.d[3] = ((wvv[u] >> 12) & 0x000F000Fu) | 0x43004300u;                  \
      union { uint4 q; short8 s; } aa; aa.q = AC[u];                           \
      tmp = __builtin_amdgcn_mfma_f32_16x16x32_bf16(aa.s, bb.s, tmp, 0, 0, 0); \
    }                                                                          \
    const uint32_t zraw = ((TT) < 8) ? qz.x : qz.y;                            \
    const float zf = (float)((zraw >> (((TT) & 7) * 4)) & 15u);                \
    const float sv2 = (mode == 2) ? scF[cg * 64 + Gc]                          \
                                  : dec16(sc16[cg * 64 + Gc], mode);           \
    const f32x4 sgv = *reinterpret_cast<const f32x4*>(sgp + Gc * 8 + (g4 & 1) * 4); \
    const float c128z = 128.0f + zf;                                           \
    D[0] += sv2 * (tmp[0] - c128z * sgv[0]);                                   \
    D[1] += sv2 * (tmp[1] - c128z * sgv[1]);                                   \
    D[2] += sv2 * (tmp[2] - c128z * sgv[2]);                                   \
    D[3] += sv2 * (tmp[3] - c128z * sgv[3]);                                   \
  } while (0)

  for (int T = 0; T < 16; T += 2) {
    GBODY(T,     q0, a0, q1, a1);
    GBODY(T + 1, q1, a1, q0, a0);
  }
#undef GBODY

  *reinterpret_cast<f32x4*>(&red[wid][lane][0]) = D;
  __syncthreads();

  if (t < 128) {
    const int r = t >> 4, cc = t & 15;
    const int ln = (r >> 2) * 16 + cc, rg = r & 3;
    float v = red[0][ln][rg] + red[1][ln][rg] + red[2][ln][rg] + red[3][ln][rg];
    const int o = blockIdx.x * 16 + cc;
    v += (mode == 2) ? bF[o] : dec16(b16[o], mode);
    const size_t idx = (size_t)r * O_TOT + o;
    if (mode == 0)      ((__hip_bfloat16*)outv)[idx] = __float2bfloat16(v);
    else if (mode == 1) ((uint16_t*)outv)[idx] = f2h_bits(v);
    else                ((float*)outv)[idx] = v;
  }
}

// --- R4 scalar fallback ---
static constexpr int NTHR = 512, O_PER_IT = 2, ITERS = 14, NBLK = 1024;
__global__ __launch_bounds__(NTHR, 1)
void wq_fallback_kernel(const uint16_t* __restrict__ x16,
                        const uint32_t* __restrict__ qweight,
                        const uint32_t* __restrict__ qzeros,
                        const uint16_t* __restrict__ sc16,
                        const uint16_t* __restrict__ b16,
                        void* __restrict__ outv,
                        const int* __restrict__ flag)
{
  __shared__ float lds[O_PER_IT][M_ROWS][NTHR];
  const int mode = *flag;
  const int t = threadIdx.x;
  const float* xF  = (const float*)x16;
  const float* scF = (const float*)sc16;
  const float* bF  = (const float*)b16;
  float xf[M_ROWS][16];
  {
    const int kbase = 16 * t;
    if (mode == 2) {
      #pragma unroll
      for (int n = 0; n < M_ROWS; ++n)
        #pragma unroll
        for (int i = 0; i < 16; ++i) xf[n][i] = xF[(size_t)n * K_TOT + kbase + i];
    } else {
      #pragma unroll
      for (int n = 0; n < M_ROWS; ++n)
        #pragma unroll
        for (int i = 0; i < 16; ++i) xf[n][i] = dec16(x16[(size_t)n * K_TOT + kbase + i], mode);
    }
  }
  const int g = t >> 3, zsh = (g & 7) * 4, zword = g >> 3;
  for (int it = 0; it < ITERS; ++it) {
    const int obase = blockIdx.x * (ITERS * O_PER_IT) + it * O_PER_IT;
    #pragma unroll
    for (int oi = 0; oi < O_PER_IT; ++oi) {
      const int o = obase + oi;
      const uint32_t zw = qzeros[o * 8 + zword];
      const float z = (float)((zw >> zsh) & 15u);
      const float s = (mode == 2) ? scF[o * 64 + g] : dec16(sc16[o * 64 + g], mode);
      const uint32_t w0 = qweight[(size_t)o * KW + 2 * t];
      const uint32_t w1 = qweight[(size_t)o * KW + 2 * t + 1];
      float d[M_ROWS];
      #pragma unroll
      for (int n = 0; n < M_ROWS; ++n) d[n] = 0.f;
      const uint32_t wvv[2] = { w0, w1 };
      #pragma unroll
      for (int w = 0; w < 2; ++w)
        #pragma unroll
        for (int j = 0; j < 8; ++j) {
          const float q = (float)((wvv[w] >> (4 * j)) & 15u);
          const float wgt = s * (q - z);
          #pragma unroll
          for (int n = 0; n < M_ROWS; ++n) d[n] = fmaf(wgt, xf[n][8 * w + j], d[n]);
        }
      #pragma unroll
      for (int n = 0; n < M_ROWS; ++n) lds[oi][n][t] = d[n];
    }
    __syncthreads();
    {
      const int wvid = t >> 6, lanei = t & 63;
      #pragma unroll
      for (int cc2 = 0; cc2 < 2; ++cc2) {
        const int p = 2 * wvid + cc2, oi = p >> 3, n = p & 7;
        float v = 0.f;
        #pragma unroll
        for (int i = 0; i < 8; ++i) v += lds[oi][n][lanei + 64 * i];
        v += __shfl_xor(v, 32); v += __shfl_xor(v, 16); v += __shfl_xor(v, 8);
        v += __shfl_xor(v, 4);  v += __shfl_xor(v, 2);  v += __shfl_xor(v, 1);
        if (lanei == 0) {
          const int o = obase + oi;
          const float b = (mode == 2) ? bF[o] : dec16(b16[o], mode);
          const float rr = v + b;
          const size_t idx = (size_t)n * O_TOT + o;
          if (mode == 0)      ((__hip_bfloat16*)outv)[idx] = __float2bfloat16(rr);
          else if (mode == 1) ((uint16_t*)outv)[idx] = f2h_bits(rr);
          else                ((float*)outv)[idx] = rr;
        }
      }
    }
    __syncthreads();
  }
}

extern "C" void kernel_launch(void* const* d_in, const int* in_sizes, int n_in,
                              void* d_out, int out_size, void* d_ws, size_t ws_size,
                              hipStream_t stream)
{
  const uint16_t* x       = (const uint16_t*)d_in[0];
  const uint32_t* qweight = (const uint32_t*)d_in[1];
  const uint32_t* qzeros  = (const uint32_t*)d_in[2];
  const uint16_t* scales  = (const uint16_t*)d_in[3];
  const uint16_t* bias    = (const uint16_t*)d_in[4];
  uint8_t* ws = (uint8_t*)d_ws;
  int* flag = (int*)d_ws;

  if (ws_size >= WS_NEED_V10) {
    float* part = (float*)(ws + WS_PART);
    int*   ctr  = (int*)(ws + WS_CTR);
    hipLaunchKernelGGL(prep_all_kernel, dim3(32), dim3(256), 0, stream, x, ws, ctr, 1);
    hipLaunchKernelGGL(wq_mfma4_kernel, dim3(3584), dim3(256), 0, stream,
                       qweight, qzeros, scales, bias, d_out, ws, part, ctr, flag);
  } else if (ws_size >= WS_NEED_R7) {
    hipLaunchKernelGGL(prep_all_kernel, dim3(32), dim3(256), 0, stream, x, ws, (int*)ws, 0);
    hipLaunchKernelGGL(wq_mfma_kernel, dim3(1792), dim3(256), 0, stream,
                       qweight, qzeros, scales, bias, d_out, ws, flag);
  } else {
    hipLaunchKernelGGL(sniff_kernel, dim3(1), dim3(64), 0, stream, x, flag);
    hipLaunchKernelGGL(wq_fallback_kernel, dim3(NBLK), dim3(NTHR), 0, stream,
                       x, qweight, qzeros, scales, bias, d_out, flag);
  }
}

// Round 11
// 38.632 us; speedup vs baseline: 11.5351x; 11.5351x over previous
//
#include <hip/hip_runtime.h>
#include <hip/hip_bf16.h>
#include <stdint.h>

typedef short short8 __attribute__((ext_vector_type(8)));
typedef float f32x4  __attribute__((ext_vector_type(4)));

static constexpr int O_TOT = 28672;
static constexpr int K_TOT = 8192;
static constexpr int M_ROWS = 8;
static constexpr int KW = 1024;            // packed int32 words per output row

// workspace layout
static constexpr size_t WS_X    = 4096;                           // 8 x 8192 bf16 = 128KB
static constexpr size_t WS_SG   = WS_X + (size_t)8 * K_TOT * 2;   // 64x8 f32 = 2KB
static constexpr size_t WS_PART = WS_SG + 64 * 8 * 4;             // f32 [64][28672] = 7.34MB
static constexpr size_t WS_NEED_V11 = WS_PART + (size_t)64 * O_TOT * 4 + 64;
static constexpr size_t WS_NEED_R7  = WS_SG + 64 * 8 * 4 + 64;

// mode: 0 = bf16, 1 = fp16, 2 = f32
__device__ __forceinline__ float dec16(uint16_t u, int mode) {
  if (mode == 0) {
    union { uint32_t i; float f; } v; v.i = ((uint32_t)u) << 16; return v.f;
  } else {
    union { uint16_t u; _Float16 h; } v; v.u = u; return (float)v.h;
  }
}
__device__ __forceinline__ uint16_t f2bf_bits(float f) {
  union { __hip_bfloat16 b; uint16_t u; } v; v.b = __float2bfloat16(f); return v.u;
}
__device__ __forceinline__ uint16_t f2h_bits(float f) {
  union { uint16_t u; _Float16 h; } v; v.h = (_Float16)f; return v.u;
}

// --- standalone sniffer (only for tiny-ws bottom tier) ---
__global__ void sniff_kernel(const uint16_t* __restrict__ x, int* __restrict__ flag) {
  const int t = threadIdx.x;
  int ce = 0, co = 0;
  #pragma unroll
  for (int i = 0; i < 2; ++i) {
    const uint4 u = *reinterpret_cast<const uint4*>(x + (size_t)(t + 64 * i) * 8);
    const uint32_t d[4] = {u.x, u.y, u.z, u.w};
    #pragma unroll
    for (int j = 0; j < 4; ++j) {
      const int elo = (d[j] >> 7)  & 0xFF;
      const int ehi = (d[j] >> 23) & 0xFF;
      ce += (elo >= 118 && elo <= 131);
      co += (ehi >= 118 && ehi <= 131);
    }
  }
  for (int d = 32; d; d >>= 1) { ce += __shfl_xor(ce, d); co += __shfl_xor(co, d); }
  if (t == 0) {
    int mode;
    if (ce > 358 && co > 358)      mode = 0;
    else if (co > 358)             mode = 2;
    else                           mode = 1;
    *flag = mode;
  }
}

// --- prep_all: self-sniff + flag + x decode/permute + group sums (verified R10) ---
__global__ __launch_bounds__(256)
void prep_all_kernel(const uint16_t* __restrict__ x16, uint8_t* __restrict__ ws) {
  __shared__ int msh[4];
  __shared__ float psum[256];
  const int t = threadIdx.x;
  const int wv = t >> 6, lane = t & 63;

  // self-sniff: all blocks classify the SAME first 1024 elements of x (L2-hot)
  int mode;
  {
    const uint4 u = reinterpret_cast<const uint4*>(x16)[t];
    const uint32_t d[4] = {u.x, u.y, u.z, u.w};
    int ce = 0, co = 0;
    #pragma unroll
    for (int j = 0; j < 4; ++j) {
      const int elo = (d[j] >> 7)  & 0xFF;
      const int ehi = (d[j] >> 23) & 0xFF;
      ce += (elo >= 118 && elo <= 131);
      co += (ehi >= 118 && ehi <= 131);
    }
    for (int s = 32; s; s >>= 1) { ce += __shfl_xor(ce, s); co += __shfl_xor(co, s); }
    if (lane == 0) msh[wv] = (ce << 16) | co;
    __syncthreads();
    int CE = 0, CO = 0;
    #pragma unroll
    for (int w = 0; w < 4; ++w) { CE += msh[w] >> 16; CO += msh[w] & 0xffff; }
    mode = (CE > 716 && CO > 716) ? 0 : ((CO > 716) ? 2 : 1);
  }
  if (blockIdx.x == 0 && t == 0) *reinterpret_cast<int*>(ws) = mode;

  // x decode -> bf16, permuted 0,4,1,5,2,6,3,7 per 8-block (verified R5-R10)
  const int tid = blockIdx.x * 256 + t;             // 32 blocks x 256 = 8192
  const int r = tid >> 10, wb = tid & 1023;
  uint16_t s[8];
  if (mode == 2) {
    const float* xF = (const float*)x16;
    #pragma unroll
    for (int j = 0; j < 8; ++j) s[j] = f2bf_bits(xF[(size_t)r * K_TOT + wb * 8 + j]);
  } else {
    const uint4 u = *reinterpret_cast<const uint4*>(x16 + (size_t)r * K_TOT + wb * 8);
    const uint32_t d[4] = {u.x, u.y, u.z, u.w};
    #pragma unroll
    for (int j = 0; j < 8; ++j) {
      const uint16_t raw = (j & 1) ? (uint16_t)(d[j >> 1] >> 16) : (uint16_t)(d[j >> 1] & 0xffffu);
      s[j] = (mode == 0) ? raw : f2bf_bits(dec16(raw, 1));
    }
  }
  uint16_t p[8];
  p[0] = s[0]; p[1] = s[4]; p[2] = s[1]; p[3] = s[5];
  p[4] = s[2]; p[5] = s[6]; p[6] = s[3]; p[7] = s[7];
  uint4 o;
  o.x = (uint32_t)p[0] | ((uint32_t)p[1] << 16);
  o.y = (uint32_t)p[2] | ((uint32_t)p[3] << 16);
  o.z = (uint32_t)p[4] | ((uint32_t)p[5] << 16);
  o.w = (uint32_t)p[6] | ((uint32_t)p[7] << 16);
  *reinterpret_cast<uint4*>((uint16_t*)(ws + WS_X) + (size_t)r * K_TOT + wb * 8) = o;

  float loc = 0.f;
  #pragma unroll
  for (int j = 0; j < 8; ++j) loc += dec16(p[j], 0);
  psum[t] = loc;
  __syncthreads();
  #pragma unroll
  for (int st = 8; st; st >>= 1) {
    if ((t & 15) < st) psum[t] += psum[t + st];
    __syncthreads();
  }
  if ((t & 15) == 0) {
    const int g = t >> 4;
    const int G = (blockIdx.x & 3) * 16 + g;
    ((float*)(ws + WS_SG))[G * 8 + r] = psum[t];
  }
}

// --- v11 main: v9 body (verified) + issue-early q loads + direct scale loads.
//     NO fence, NO atomics; partials to ws, separate reduce. ---
__global__ __launch_bounds__(256)
void wq_mfma5_kernel(const uint32_t* __restrict__ qweight,
                     const uint32_t* __restrict__ qzeros,
                     const uint16_t* __restrict__ sc16,
                     const uint8_t* __restrict__ ws,
                     float* __restrict__ part,
                     const int* __restrict__ flag)
{
  __shared__ __align__(16) uint4 xl[8 * 129];   // 16.5KB
  __shared__ float sgl[64];
  const int mode = *flag;
  const int t = threadIdx.x, wid = t >> 6, lane = t & 63;
  const int c = lane & 15, g4 = lane >> 4;
  const int bi = blockIdx.x;
  const int ct = bi >> 3, kq = bi & 7;          // kq fast: streaming sweep
  const int cg = ct * 64 + wid * 16 + c;

  // issue ALL 8 qweight loads FIRST: latency hides under x staging + barrier
  const uint32_t* qp = qweight + (size_t)cg * KW + kq * 128;
  uint4 q[8];
  #pragma unroll
  for (int T = 0; T < 8; ++T)
    q[T] = *reinterpret_cast<const uint4*>(qp + 16 * T + 4 * g4);

  const uint32_t qzw = qzeros[cg * 8 + kq];     // 8 zeros of this chunk
  float sv[8];
  if (mode == 2) {
    const float* sp = (const float*)sc16 + (size_t)cg * 64 + kq * 8;
    const f32x4 s0 = *reinterpret_cast<const f32x4*>(sp);
    const f32x4 s1 = *reinterpret_cast<const f32x4*>(sp + 4);
    sv[0] = s0[0]; sv[1] = s0[1]; sv[2] = s0[2]; sv[3] = s0[3];
    sv[4] = s1[0]; sv[5] = s1[1]; sv[6] = s1[2]; sv[7] = s1[3];
  } else {
    const uint4 sr = *reinterpret_cast<const uint4*>(sc16 + (size_t)cg * 64 + kq * 8);
    const uint32_t sd[4] = {sr.x, sr.y, sr.z, sr.w};
    #pragma unroll
    for (int j = 0; j < 4; ++j) {
      sv[2*j]   = dec16((uint16_t)(sd[j] & 0xffffu), mode);
      sv[2*j+1] = dec16((uint16_t)(sd[j] >> 16), mode);
    }
  }

  // stage x chunk (1024 uint4) + group sums
  {
    const uint4* src = (const uint4*)(ws + WS_X);
    #pragma unroll
    for (int j = 0; j < 4; ++j) {
      const int idx = j * 256 + t;
      const int r = idx >> 7, w = idx & 127;
      xl[r * 129 + w] = src[(size_t)r * 1024 + kq * 128 + w];
    }
    if (t < 64) sgl[t] = ((const float*)(ws + WS_SG))[kq * 64 + t];
  }
  __syncthreads();

  f32x4 D = {0.f, 0.f, 0.f, 0.f};
  #pragma unroll
  for (int T = 0; T < 8; ++T) {
    const uint4 a0 = xl[(c & 7) * 129 + 16 * T + 4 * g4 + 0];
    const uint4 a1 = xl[(c & 7) * 129 + 16 * T + 4 * g4 + 1];
    const uint4 a2 = xl[(c & 7) * 129 + 16 * T + 4 * g4 + 2];
    const uint4 a3 = xl[(c & 7) * 129 + 16 * T + 4 * g4 + 3];
    const f32x4 sgv = *reinterpret_cast<const f32x4*>(&sgl[T * 8 + (g4 & 1) * 4]);

    f32x4 tmp = {0.f, 0.f, 0.f, 0.f};
    const uint32_t wvv[4] = {q[T].x, q[T].y, q[T].z, q[T].w};
    const uint4   av[4] = {a0, a1, a2, a3};
    #pragma unroll
    for (int u = 0; u < 4; ++u) {
      union { uint32_t d[4]; short8 s; } bb;
      bb.d[0] = ( wvv[u]        & 0x000F000Fu) | 0x43004300u;
      bb.d[1] = ((wvv[u] >> 4)  & 0x000F000Fu) | 0x43004300u;
      bb.d[2] = ((wvv[u] >> 8)  & 0x000F000Fu) | 0x43004300u;
      bb.d[3] = ((wvv[u] >> 12) & 0x000F000Fu) | 0x43004300u;
      union { uint4 q; short8 s; } aa; aa.q = av[u];
      tmp = __builtin_amdgcn_mfma_f32_16x16x32_bf16(aa.s, bb.s, tmp, 0, 0, 0);
    }
    const float zf = (float)((qzw >> (T * 4)) & 15u);
    const float c128z = 128.0f + zf;
    D[0] += sv[T] * (tmp[0] - c128z * sgv[0]);
    D[1] += sv[T] * (tmp[1] - c128z * sgv[1]);
    D[2] += sv[T] * (tmp[2] - c128z * sgv[2]);
    D[3] += sv[T] * (tmp[3] - c128z * sgv[3]);
  }

  if (g4 < 2) {
    #pragma unroll
    for (int reg = 0; reg < 4; ++reg) {
      const int r = g4 * 4 + reg;               // D row = (lane>>4)*4 + reg (m89)
      part[((size_t)kq * 8 + r) * O_TOT + cg] = D[reg];
    }
  }
}

// --- reduce: sum 8 k-chunk partials + bias -> output (verified R9) ---
__global__ __launch_bounds__(256)
void reduce_kernel(const float* __restrict__ part,
                   const uint16_t* __restrict__ b16,
                   void* __restrict__ outv,
                   const int* __restrict__ flag)
{
  const int mode = *flag;
  const int idx = blockIdx.x * 256 + threadIdx.x;  // 224 blocks: 57344 threads
  const int lin = idx * 4;
  const int r = lin / O_TOT, o = lin - r * O_TOT;
  f32x4 s = {0.f, 0.f, 0.f, 0.f};
  #pragma unroll
  for (int k = 0; k < 8; ++k) {
    const f32x4 p = *reinterpret_cast<const f32x4*>(part + ((size_t)k * 8 + r) * O_TOT + o);
    s[0] += p[0]; s[1] += p[1]; s[2] += p[2]; s[3] += p[3];
  }
  if (mode == 2) {
    const float* bF = (const float*)b16;
    const f32x4 b = *reinterpret_cast<const f32x4*>(bF + o);
    f32x4 w = {s[0] + b[0], s[1] + b[1], s[2] + b[2], s[3] + b[3]};
    *reinterpret_cast<f32x4*>((float*)outv + (size_t)r * O_TOT + o) = w;
  } else {
    const uint2 bb = *reinterpret_cast<const uint2*>(b16 + o);
    const uint16_t bu[4] = {(uint16_t)(bb.x & 0xffffu), (uint16_t)(bb.x >> 16),
                            (uint16_t)(bb.y & 0xffffu), (uint16_t)(bb.y >> 16)};
    uint16_t w[4];
    #pragma unroll
    for (int j = 0; j < 4; ++j) {
      const float v = s[j] + dec16(bu[j], mode);
      w[j] = (mode == 0) ? f2bf_bits(v) : f2h_bits(v);
    }
    uint2 pk;
    pk.x = (uint32_t)w[0] | ((uint32_t)w[1] << 16);
    pk.y = (uint32_t)w[2] | ((uint32_t)w[3] << 16);
    *reinterpret_cast<uint2*>((uint16_t*)outv + (size_t)r * O_TOT + o) = pk;
  }
}

// --- R7 main (verified) as mid-tier fallback ---
__global__ __launch_bounds__(256)
void wq_mfma_kernel(const uint32_t* __restrict__ qweight,
                    const uint32_t* __restrict__ qzeros,
                    const uint16_t* __restrict__ sc16,
                    const uint16_t* __restrict__ b16,
                    void* __restrict__ outv,
                    const uint8_t* __restrict__ ws,
                    const int* __restrict__ flag)
{
  __shared__ float red[4][64][4];
  const int mode = *flag;
  const float* scF = (const float*)sc16;
  const float* bF  = (const float*)b16;
  const int t = threadIdx.x, wid = t >> 6, lane = t & 63;
  const int c = lane & 15, g4 = lane >> 4;
  const int cg = blockIdx.x * 16 + c;

  const uint16_t* xb  = (const uint16_t*)(ws + WS_X);
  const float*    sgp = (const float*)(ws + WS_SG);
  const uint32_t* qp  = qweight + (size_t)cg * KW;
  const uint4*  abase = (const uint4*)(xb + (size_t)(c & 7) * K_TOT);
  const int G0   = wid * 16;
  const int boff = 4 * g4;
  const uint2 qz = *reinterpret_cast<const uint2*>(qzeros + cg * 8 + wid * 2);

  f32x4 D = {0.f, 0.f, 0.f, 0.f};
  uint4 q0 = *reinterpret_cast<const uint4*>(qp + 16 * G0 + boff);
  uint4 a0[4], a1[4]; uint4 q1;
  #pragma unroll
  for (int u = 0; u < 4; ++u) a0[u] = abase[16 * G0 + boff + u];

#define GBODY(TT, QC, AC, QN, AN)                                              \
  do {                                                                         \
    const int Gc = G0 + (TT);                                                  \
    const int Gn = (Gc + 1 <= 63) ? Gc + 1 : 63;                               \
    QN = *reinterpret_cast<const uint4*>(qp + 16 * Gn + boff);                 \
    AN[0] = abase[16 * Gn + boff + 0];                                         \
    AN[1] = abase[16 * Gn + boff + 1];                                         \
    AN[2] = abase[16 * Gn + boff + 2];                                         \
    AN[3] = abase[16 * Gn + boff + 3];                                         \
    f32x4 tmp = {0.f, 0.f, 0.f, 0.f};                                          \
    const uint32_t wvv[4] = {QC.x, QC.y, QC.z, QC.w};                          \
    _Pragma("unroll")                                                          \
    for (int u = 0; u < 4; ++u) {                                              \
      union { uint32_t d[4]; short8 s; } bb;                                   \
      bb.d[0] = ( wvv[u]        & 0x000F000Fu) | 0x43004300u;                  \
      bb.d[1] = ((wvv[u] >> 4)  & 0x000F000Fu) | 0x43004300u;                  \
      bb.d[2] = ((wvv[u] >> 8)  & 0x000F000Fu) | 0x43004300u;                  \
      bb.d[3] = ((wvv[u] >> 12) & 0x000F000Fu) | 0x43004300u;                  \
      union { uint4 q; short8 s; } aa; aa.q = AC[u];                           \
      tmp = __builtin_amdgcn_mfma_f32_16x16x32_bf16(aa.s, bb.s, tmp, 0, 0, 0); \
    }                                                                          \
    const uint32_t zraw = ((TT) < 8) ? qz.x : qz.y;                            \
    const float zf = (float)((zraw >> (((TT) & 7) * 4)) & 15u);                \
    const float sv2 = (mode == 2) ? scF[cg * 64 + Gc]                          \
                                  : dec16(sc16[cg * 64 + Gc], mode);           \
    const f32x4 sgv = *reinterpret_cast<const f32x4*>(sgp + Gc * 8 + (g4 & 1) * 4); \
    const float c128z = 128.0f + zf;                                           \
    D[0] += sv2 * (tmp[0] - c128z * sgv[0]);                                   \
    D[1] += sv2 * (tmp[1] - c128z * sgv[1]);                                   \
    D[2] += sv2 * (tmp[2] - c128z * sgv[2]);                                   \
    D[3] += sv2 * (tmp[3] - c128z * sgv[3]);                                   \
  } while (0)

  for (int T = 0; T < 16; T += 2) {
    GBODY(T,     q0, a0, q1, a1);
    GBODY(T + 1, q1, a1, q0, a0);
  }
#undef GBODY

  *reinterpret_cast<f32x4*>(&red[wid][lane][0]) = D;
  __syncthreads();

  if (t < 128) {
    const int r = t >> 4, cc = t & 15;
    const int ln = (r >> 2) * 16 + cc, rg = r & 3;
    float v = red[0][ln][rg] + red[1][ln][rg] + red[2][ln][rg] + red[3][ln][rg];
    const int o = blockIdx.x * 16 + cc;
    v += (mode == 2) ? bF[o] : dec16(b16[o], mode);
    const size_t idx = (size_t)r * O_TOT + o;
    if (mode == 0)      ((__hip_bfloat16*)outv)[idx] = __float2bfloat16(v);
    else if (mode == 1) ((uint16_t*)outv)[idx] = f2h_bits(v);
    else                ((float*)outv)[idx] = v;
  }
}

// --- R4 scalar fallback ---
static constexpr int NTHR = 512, O_PER_IT = 2, ITERS = 14, NBLK = 1024;
__global__ __launch_bounds__(NTHR, 1)
void wq_fallback_kernel(const uint16_t* __restrict__ x16,
                        const uint32_t* __restrict__ qweight,
                        const uint32_t* __restrict__ qzeros,
                        const uint16_t* __restrict__ sc16,
                        const uint16_t* __restrict__ b16,
                        void* __restrict__ outv,
                        const int* __restrict__ flag)
{
  __shared__ float lds[O_PER_IT][M_ROWS][NTHR];
  const int mode = *flag;
  const int t = threadIdx.x;
  const float* xF  = (const float*)x16;
  const float* scF = (const float*)sc16;
  const float* bF  = (const float*)b16;
  float xf[M_ROWS][16];
  {
    const int kbase = 16 * t;
    if (mode == 2) {
      #pragma unroll
      for (int n = 0; n < M_ROWS; ++n)
        #pragma unroll
        for (int i = 0; i < 16; ++i) xf[n][i] = xF[(size_t)n * K_TOT + kbase + i];
    } else {
      #pragma unroll
      for (int n = 0; n < M_ROWS; ++n)
        #pragma unroll
        for (int i = 0; i < 16; ++i) xf[n][i] = dec16(x16[(size_t)n * K_TOT + kbase + i], mode);
    }
  }
  const int g = t >> 3, zsh = (g & 7) * 4, zword = g >> 3;
  for (int it = 0; it < ITERS; ++it) {
    const int obase = blockIdx.x * (ITERS * O_PER_IT) + it * O_PER_IT;
    #pragma unroll
    for (int oi = 0; oi < O_PER_IT; ++oi) {
      const int o = obase + oi;
      const uint32_t zw = qzeros[o * 8 + zword];
      const float z = (float)((zw >> zsh) & 15u);
      const float s = (mode == 2) ? scF[o * 64 + g] : dec16(sc16[o * 64 + g], mode);
      const uint32_t w0 = qweight[(size_t)o * KW + 2 * t];
      const uint32_t w1 = qweight[(size_t)o * KW + 2 * t + 1];
      float d[M_ROWS];
      #pragma unroll
      for (int n = 0; n < M_ROWS; ++n) d[n] = 0.f;
      const uint32_t wvv[2] = { w0, w1 };
      #pragma unroll
      for (int w = 0; w < 2; ++w)
        #pragma unroll
        for (int j = 0; j < 8; ++j) {
          const float q = (float)((wvv[w] >> (4 * j)) & 15u);
          const float wgt = s * (q - z);
          #pragma unroll
          for (int n = 0; n < M_ROWS; ++n) d[n] = fmaf(wgt, xf[n][8 * w + j], d[n]);
        }
      #pragma unroll
      for (int n = 0; n < M_ROWS; ++n) lds[oi][n][t] = d[n];
    }
    __syncthreads();
    {
      const int wvid = t >> 6, lanei = t & 63;
      #pragma unroll
      for (int cc2 = 0; cc2 < 2; ++cc2) {
        const int p = 2 * wvid + cc2, oi = p >> 3, n = p & 7;
        float v = 0.f;
        #pragma unroll
        for (int i = 0; i < 8; ++i) v += lds[oi][n][lanei + 64 * i];
        v += __shfl_xor(v, 32); v += __shfl_xor(v, 16); v += __shfl_xor(v, 8);
        v += __shfl_xor(v, 4);  v += __shfl_xor(v, 2);  v += __shfl_xor(v, 1);
        if (lanei == 0) {
          const int o = obase + oi;
          const float b = (mode == 2) ? bF[o] : dec16(b16[o], mode);
          const float rr = v + b;
          const size_t idx = (size_t)n * O_TOT + o;
          if (mode == 0)      ((__hip_bfloat16*)outv)[idx] = __float2bfloat16(rr);
          else if (mode == 1) ((uint16_t*)outv)[idx] = f2h_bits(rr);
          else                ((float*)outv)[idx] = rr;
        }
      }
    }
    __syncthreads();
  }
}

extern "C" void kernel_launch(void* const* d_in, const int* in_sizes, int n_in,
                              void* d_out, int out_size, void* d_ws, size_t ws_size,
                              hipStream_t stream)
{
  const uint16_t* x       = (const uint16_t*)d_in[0];
  const uint32_t* qweight = (const uint32_t*)d_in[1];
  const uint32_t* qzeros  = (const uint32_t*)d_in[2];
  const uint16_t* scales  = (const uint16_t*)d_in[3];
  const uint16_t* bias    = (const uint16_t*)d_in[4];
  uint8_t* ws = (uint8_t*)d_ws;
  int* flag = (int*)d_ws;

  if (ws_size >= WS_NEED_V11) {
    float* part = (float*)(ws + WS_PART);
    hipLaunchKernelGGL(prep_all_kernel, dim3(32), dim3(256), 0, stream, x, ws);
    hipLaunchKernelGGL(wq_mfma5_kernel, dim3(3584), dim3(256), 0, stream,
                       qweight, qzeros, scales, ws, part, flag);
    hipLaunchKernelGGL(reduce_kernel, dim3(224), dim3(256), 0, stream,
                       part, bias, d_out, flag);
  } else if (ws_size >= WS_NEED_R7) {
    hipLaunchKernelGGL(prep_all_kernel, dim3(32), dim3(256), 0, stream, x, ws);
    hipLaunchKernelGGL(wq_mfma_kernel, dim3(1792), dim3(256), 0, stream,
                       qweight, qzeros, scales, bias, d_out, ws, flag);
  } else {
    hipLaunchKernelGGL(sniff_kernel, dim3(1), dim3(64), 0, stream, x, flag);
    hipLaunchKernelGGL(wq_fallback_kernel, dim3(NBLK), dim3(NTHR), 0, stream,
                       x, qweight, qzeros, scales, bias, d_out, flag);
  }
}